// Round 5
// baseline (1632.117 us; speedup 1.0000x reference)
//
#include <hip/hip_runtime.h>

#define NN 50000
#define NE 800000

// ================= CSR build: hist / inv / scan / scatter =================
__global__ void hist_kernel(const int* __restrict__ recv, int* __restrict__ cnt) {
    int i = blockIdx.x * 256 + threadIdx.x;
    if (i < NE) atomicAdd(&cnt[recv[i]], 1);
}

__global__ void inv_kernel(const int* __restrict__ cnt, float* __restrict__ inv) {
    int i = blockIdx.x * 256 + threadIdx.x;
    if (i < NN) inv[i] = 1.0f / (float)max(cnt[i], 1);
}

__global__ void scan1_kernel(const int* __restrict__ cnt, int* __restrict__ excl,
                             int* __restrict__ bsum) {
    const int i = blockIdx.x * 256 + threadIdx.x;
    const int lane = threadIdx.x & 63, wid = threadIdx.x >> 6;
    int orig = (i < NN) ? cnt[i] : 0;
    int x = orig;
    #pragma unroll
    for (int off = 1; off < 64; off <<= 1) {
        int y = __shfl_up(x, off, 64);
        if (lane >= off) x += y;
    }
    __shared__ int ws[4];
    if (lane == 63) ws[wid] = x;
    __syncthreads();
    int add = 0;
    for (int w = 0; w < wid; ++w) add += ws[w];
    x += add;
    if (i < NN) excl[i] = x - orig;
    if (threadIdx.x == 255) bsum[blockIdx.x] = x;
}

__global__ void scan2_kernel(int* __restrict__ bsum, int nb) {
    const int t = threadIdx.x;
    const int lane = t & 63, wid = t >> 6;
    int orig = (t < nb) ? bsum[t] : 0;
    int x = orig;
    #pragma unroll
    for (int off = 1; off < 64; off <<= 1) {
        int y = __shfl_up(x, off, 64);
        if (lane >= off) x += y;
    }
    __shared__ int ws[4];
    if (lane == 63) ws[wid] = x;
    __syncthreads();
    int add = 0;
    for (int w = 0; w < wid; ++w) add += ws[w];
    x += add;
    __syncthreads();
    if (t < nb) bsum[t] = x - orig;
}

__global__ void scan3_kernel(int* __restrict__ excl, const int* __restrict__ bsum) {
    const int i = blockIdx.x * 256 + threadIdx.x;
    if (i < NN) excl[i] += bsum[blockIdx.x];
    if (i == 0) excl[NN] = NE;
}

__global__ void scatter_kernel(const int* __restrict__ recv, const int* __restrict__ row_start,
                               int* __restrict__ cursor, int* __restrict__ eidx) {
    int i = blockIdx.x * 256 + threadIdx.x;
    if (i < NE) {
        int r = recv[i];
        int p = row_start[r] + atomicAdd(&cursor[r], 1);
        eidx[p] = i;
    }
}

// ================= edge GEMM (register A-streaming) =======================
// out[e] = relu(A[e]@W + b + P[s[e]] + Q[r[e]]). A rows private per thread,
// streamed global->reg; only W in LDS. A and out ALIAS for l>=1 (in-place):
// -> no __restrict__ on A/out, and a __syncthreads() between the k-loop and
// the epilogue so ALL tile reads complete before ANY tile write (the race
// that broke rounds 3/4: wave 0 wrote rows wave 3 was still reading).
__launch_bounds__(256, 2)
__global__ void gemm_edge_kernel(const float* A,
                                 const float* __restrict__ W,     // [64][64]
                                 const float* __restrict__ bias,  // [64]
                                 const float* __restrict__ P,
                                 const float* __restrict__ Q,
                                 const int* __restrict__ senders,
                                 const int* __restrict__ receivers,
                                 float* out, int M) {
    __shared__ float w_lds[64 * 64];
    const int tid = threadIdx.x;
    for (int i = tid; i < 4096; i += 256) w_lds[i] = W[i];
    const int et = tid & 31;
    const int tc = tid >> 5;
    const int c0 = tc * 8;
    const float4 bv0 = *(const float4*)(bias + c0);
    const float4 bv1 = *(const float4*)(bias + c0 + 4);
    const int base = blockIdx.x << 8;
    int aoff[8];
    #pragma unroll
    for (int t = 0; t < 8; ++t) {
        int e = base + et + 32 * t;
        if (e > M - 1) e = M - 1;
        aoff[t] = e * 64;
    }
    __syncthreads();

    float4 acc0[8], acc1[8];
    #pragma unroll
    for (int t = 0; t < 8; ++t) {
        acc0[t] = make_float4(0.f, 0.f, 0.f, 0.f);
        acc1[t] = make_float4(0.f, 0.f, 0.f, 0.f);
    }

    #pragma unroll 1
    for (int k0 = 0; k0 < 64; k0 += 8) {
        float evs[8][8];
        #pragma unroll
        for (int t = 0; t < 8; ++t) {
            const float4 a = *(const float4*)(A + aoff[t] + k0);
            const float4 b = *(const float4*)(A + aoff[t] + k0 + 4);
            evs[t][0] = a.x; evs[t][1] = a.y; evs[t][2] = a.z; evs[t][3] = a.w;
            evs[t][4] = b.x; evs[t][5] = b.y; evs[t][6] = b.z; evs[t][7] = b.w;
        }
        #pragma unroll
        for (int kk = 0; kk < 8; ++kk) {
            const float4 w0 = *(const float4*)&w_lds[(k0 + kk) * 64 + c0];
            const float4 w1 = *(const float4*)&w_lds[(k0 + kk) * 64 + c0 + 4];
            #pragma unroll
            for (int t = 0; t < 8; ++t) {
                const float ev = evs[t][kk];
                acc0[t].x = fmaf(ev, w0.x, acc0[t].x);
                acc0[t].y = fmaf(ev, w0.y, acc0[t].y);
                acc0[t].z = fmaf(ev, w0.z, acc0[t].z);
                acc0[t].w = fmaf(ev, w0.w, acc0[t].w);
                acc1[t].x = fmaf(ev, w1.x, acc1[t].x);
                acc1[t].y = fmaf(ev, w1.y, acc1[t].y);
                acc1[t].z = fmaf(ev, w1.z, acc1[t].z);
                acc1[t].w = fmaf(ev, w1.w, acc1[t].w);
            }
        }
    }

    // All A-tile reads are consumed into acc registers by every thread before
    // this barrier; only after it may any thread overwrite the (aliased) tile.
    __syncthreads();

    #pragma unroll
    for (int t = 0; t < 8; ++t) {
        const int e = base + et + 32 * t;
        if (e < M) {
            const int s = senders[e];
            const int r = receivers[e];
            const float4 p0 = *(const float4*)(P + (size_t)s * 64 + c0);
            const float4 p1 = *(const float4*)(P + (size_t)s * 64 + c0 + 4);
            const float4 q0 = *(const float4*)(Q + (size_t)r * 64 + c0);
            const float4 q1 = *(const float4*)(Q + (size_t)r * 64 + c0 + 4);
            float4 o0, o1;
            o0.x = fmaxf(acc0[t].x + bv0.x + p0.x + q0.x, 0.f);
            o0.y = fmaxf(acc0[t].y + bv0.y + p0.y + q0.y, 0.f);
            o0.z = fmaxf(acc0[t].z + bv0.z + p0.z + q0.z, 0.f);
            o0.w = fmaxf(acc0[t].w + bv0.w + p0.w + q0.w, 0.f);
            o1.x = fmaxf(acc1[t].x + bv1.x + p1.x + q1.x, 0.f);
            o1.y = fmaxf(acc1[t].y + bv1.y + p1.y + q1.y, 0.f);
            o1.z = fmaxf(acc1[t].z + bv1.z + p1.z + q1.z, 0.f);
            o1.w = fmaxf(acc1[t].w + bv1.w + p1.w + q1.w, 0.f);
            *(float4*)(out + (size_t)e * 64 + c0) = o0;
            *(float4*)(out + (size_t)e * 64 + c0 + 4) = o1;
        }
    }
}

// ================= generic M x 64 x 64 GEMM (round-2, for P/Q) ============
__launch_bounds__(256, 3)
__global__ void gemm64_kernel(const float* __restrict__ A, int M,
                              const float* __restrict__ W,     // [64][64] k-major
                              const float* __restrict__ bias,  // [64] or null
                              const float* __restrict__ P,     // [NN][64] or null
                              const float* __restrict__ Q,     // [NN][64] or null
                              const int* __restrict__ senders,
                              const int* __restrict__ receivers,
                              int do_relu,
                              float* __restrict__ out) {
    __shared__ float w_lds[64 * 64];
    __shared__ float e_lds[128 * 66];
    const int tid = threadIdx.x;
    for (int i = tid; i < 4096; i += 256) w_lds[i] = W[i];
    const int te = tid & 15;
    const int tc = tid >> 4;
    const int c0 = tc * 4;
    float4 bv = make_float4(0.f, 0.f, 0.f, 0.f);
    if (bias) bv = *(const float4*)(bias + c0);
    const int srow = tid >> 1, shalf = tid & 1;
    const int ntiles = (M + 127) >> 7;

    for (int t = blockIdx.x; t < ntiles; t += gridDim.x) {
        const int base = t << 7;
        __syncthreads();
        {
            int g = base + srow;
            if (g > M - 1) g = M - 1;
            const float4* src = (const float4*)(A + (size_t)g * 64) + shalf * 8;
            float* dst = &e_lds[srow * 66 + shalf * 32];
            #pragma unroll
            for (int j = 0; j < 8; ++j) {
                float4 v = src[j];
                dst[j * 4 + 0] = v.x; dst[j * 4 + 1] = v.y;
                dst[j * 4 + 2] = v.z; dst[j * 4 + 3] = v.w;
            }
        }
        __syncthreads();

        float4 acc[8];
        #pragma unroll
        for (int i = 0; i < 8; ++i) acc[i] = make_float4(0.f, 0.f, 0.f, 0.f);

        #pragma unroll 4
        for (int k = 0; k < 64; ++k) {
            const float4 wv = *(const float4*)&w_lds[k * 64 + c0];
            #pragma unroll
            for (int i = 0; i < 8; ++i) {
                const float ev = e_lds[(te + 16 * i) * 66 + k];
                acc[i].x = fmaf(ev, wv.x, acc[i].x);
                acc[i].y = fmaf(ev, wv.y, acc[i].y);
                acc[i].z = fmaf(ev, wv.z, acc[i].z);
                acc[i].w = fmaf(ev, wv.w, acc[i].w);
            }
        }

        #pragma unroll
        for (int i = 0; i < 8; ++i) {
            const int e = base + te + 16 * i;
            if (e < M) {
                float4 o = acc[i];
                o.x += bv.x; o.y += bv.y; o.z += bv.z; o.w += bv.w;
                if (P) {
                    const float4 pv = *(const float4*)(P + (size_t)senders[e] * 64 + c0);
                    o.x += pv.x; o.y += pv.y; o.z += pv.z; o.w += pv.w;
                }
                if (Q) {
                    const float4 qv = *(const float4*)(Q + (size_t)receivers[e] * 64 + c0);
                    o.x += qv.x; o.y += qv.y; o.z += qv.z; o.w += qv.w;
                }
                if (do_relu) {
                    o.x = fmaxf(o.x, 0.f); o.y = fmaxf(o.y, 0.f);
                    o.z = fmaxf(o.z, 0.f); o.w = fmaxf(o.w, 0.f);
                }
                *(float4*)(out + (size_t)e * 64 + c0) = o;
            }
        }
    }
}

// ================= segmented mean aggregation (CSR, atomic-free) ==========
__launch_bounds__(256, 8)
__global__ void agg_kernel(const float* __restrict__ ebuf, const int* __restrict__ eidx,
                           const int* __restrict__ row_start, const float* __restrict__ inv,
                           float* __restrict__ agg) {
    const int lane = threadIdx.x & 63;
    const int w = (blockIdx.x * 256 + threadIdx.x) >> 6;
    const int nw = (gridDim.x * 256) >> 6;
    for (int v = w; v < NN; v += nw) {
        const int s = row_start[v], e = row_start[v + 1];
        float sum = 0.f;
        #pragma unroll 4
        for (int j = s; j < e; ++j) {
            const int ed = eidx[j];
            sum += ebuf[(size_t)ed * 64 + lane];
        }
        agg[(size_t)v * 64 + lane] = sum * inv[v];
    }
}

// ================= node update (round-2): relu([nodes|agg] @ Wn + bn) =====
__launch_bounds__(256, 3)
__global__ void node_kernel(const float* __restrict__ nodes_in,
                            const float* __restrict__ agg,
                            const float* __restrict__ W,     // [128][64]
                            const float* __restrict__ bias,  // [64]
                            float* __restrict__ out) {
    __shared__ float w_lds[128 * 64];
    __shared__ float e_lds[128 * 33];
    const int tid = threadIdx.x;
    for (int i = tid; i < 8192; i += 256) w_lds[i] = W[i];
    const int te = tid & 15, tc = tid >> 4, c0 = tc * 4;
    const float4 bv = *(const float4*)(bias + c0);
    const int srow = tid >> 1, shalf = tid & 1;
    const int ntiles = (NN + 127) >> 7;

    for (int t = blockIdx.x; t < ntiles; t += gridDim.x) {
        const int base = t << 7;
        float4 acc[8];
        #pragma unroll
        for (int i = 0; i < 8; ++i) acc[i] = make_float4(0.f, 0.f, 0.f, 0.f);

        #pragma unroll
        for (int c = 0; c < 4; ++c) {
            const float* src0 = (c < 2) ? nodes_in : agg;
            const int coff = (c & 1) * 32;
            __syncthreads();
            {
                int g = base + srow;
                if (g > NN - 1) g = NN - 1;
                const float4* src = (const float4*)(src0 + (size_t)g * 64 + coff) + shalf * 4;
                float* dst = &e_lds[srow * 33 + shalf * 16];
                #pragma unroll
                for (int j = 0; j < 4; ++j) {
                    float4 v = src[j];
                    dst[j * 4 + 0] = v.x; dst[j * 4 + 1] = v.y;
                    dst[j * 4 + 2] = v.z; dst[j * 4 + 3] = v.w;
                }
            }
            __syncthreads();
            #pragma unroll 4
            for (int k = 0; k < 32; ++k) {
                const float4 wv = *(const float4*)&w_lds[(c * 32 + k) * 64 + c0];
                #pragma unroll
                for (int i = 0; i < 8; ++i) {
                    const float ev = e_lds[(te + 16 * i) * 33 + k];
                    acc[i].x = fmaf(ev, wv.x, acc[i].x);
                    acc[i].y = fmaf(ev, wv.y, acc[i].y);
                    acc[i].z = fmaf(ev, wv.z, acc[i].z);
                    acc[i].w = fmaf(ev, wv.w, acc[i].w);
                }
            }
        }

        #pragma unroll
        for (int i = 0; i < 8; ++i) {
            const int v = base + te + 16 * i;
            if (v < NN) {
                float4 o = acc[i];
                o.x = fmaxf(o.x + bv.x, 0.f); o.y = fmaxf(o.y + bv.y, 0.f);
                o.z = fmaxf(o.z + bv.z, 0.f); o.w = fmaxf(o.w + bv.w, 0.f);
                *(float4*)(out + (size_t)v * 64 + c0) = o;
            }
        }
    }
}

// ================= final (round-2): LN + MLP + projection =================
__launch_bounds__(256, 2)
__global__ void final_kernel(const float* __restrict__ nodes,
                             const float* __restrict__ gamma,
                             const float* __restrict__ beta,
                             const float* __restrict__ W1, const float* __restrict__ b1,
                             const float* __restrict__ W2, const float* __restrict__ b2,
                             const float* __restrict__ Wp, const float* __restrict__ bp,
                             float* __restrict__ out) {
    __shared__ float w1_lds[64 * 128];
    __shared__ float w2_lds[128 * 64];
    const int t = threadIdx.x;
    for (int i = t; i < 64 * 128; i += 256) w1_lds[i] = W1[i];
    for (int i = t; i < 128 * 64; i += 256) w2_lds[i] = W2[i];
    const int lane = t & 63;
    const int wid  = t >> 6;
    const float gm  = gamma[lane], bt = beta[lane];
    const float b1a = b1[lane], b1b = b1[64 + lane];
    const float b2l = b2[lane];
    const float wpl = Wp[lane];
    const float bp0 = bp[0];
    __syncthreads();

    for (int v = blockIdx.x * 4 + wid; v < NN; v += gridDim.x * 4) {
        const float x = nodes[(size_t)v * 64 + lane];
        float s = x;
        #pragma unroll
        for (int off = 32; off; off >>= 1) s += __shfl_xor(s, off, 64);
        const float mu = s * (1.0f / 64.0f);
        const float d  = x - mu;
        float q = d * d;
        #pragma unroll
        for (int off = 32; off; off >>= 1) q += __shfl_xor(q, off, 64);
        const float xn = d * rsqrtf(q * (1.0f / 64.0f) + 1e-5f) * gm + bt;

        float h0 = 0.f, h1 = 0.f;
        #pragma unroll 8
        for (int k = 0; k < 64; ++k) {
            const float xk = __shfl(xn, k, 64);
            h0 += xk * w1_lds[k * 128 + lane];
            h1 += xk * w1_lds[k * 128 + 64 + lane];
        }
        h0 = fmaxf(h0 + b1a, 0.f);
        h1 = fmaxf(h1 + b1b, 0.f);

        float o = 0.f;
        #pragma unroll 8
        for (int k = 0; k < 128; ++k) {
            const float hk = __shfl((k < 64) ? h0 : h1, k & 63, 64);
            o += hk * w2_lds[k * 64 + lane];
        }
        o += b2l;

        float p = o * wpl;
        #pragma unroll
        for (int off = 32; off; off >>= 1) p += __shfl_xor(p, off, 64);
        if (lane == 0) out[v] = p + bp0;
    }
}

extern "C" void kernel_launch(void* const* d_in, const int* in_sizes, int n_in,
                              void* d_out, int out_size, void* d_ws, size_t ws_size,
                              hipStream_t stream) {
    const float* nodes     = (const float*)d_in[0];
    const float* edges     = (const float*)d_in[1];
    const int*   senders   = (const int*)d_in[2];
    const int*   receivers = (const int*)d_in[3];
    const float* We        = (const float*)d_in[4];
    const float* be        = (const float*)d_in[5];
    const float* Wn        = (const float*)d_in[6];
    const float* bn        = (const float*)d_in[7];
    const float* gamma     = (const float*)d_in[8];
    const float* beta      = (const float*)d_in[9];
    const float* W1        = (const float*)d_in[10];
    const float* b1        = (const float*)d_in[11];
    const float* W2        = (const float*)d_in[12];
    const float* b2        = (const float*)d_in[13];
    const float* Wp        = (const float*)d_in[14];
    const float* bp        = (const float*)d_in[15];
    float* out = (float*)d_out;

    float* ws        = (float*)d_ws;
    float* edges_buf = ws;                                  // [NE][64] 204.8 MB
    float* Pbuf      = edges_buf + (size_t)NE * 64;         // [NN][64] (reused as agg)
    float* Qbuf      = Pbuf + (size_t)NN * 64;              // [NN][64]
    float* nodes_buf = Qbuf + (size_t)NN * 64;              // [NN][64]
    int*   cnt_i     = (int*)(nodes_buf + (size_t)NN * 64); // [NN]
    int*   row_start = cnt_i + NN;                          // [NN+1]
    int*   cursor    = row_start + NN + 1;                  // [NN]
    int*   eidx      = cursor + NN;                         // [NE]
    int*   bsum      = eidx + NE;                           // [256]
    float* inv       = (float*)(bsum + 256);                // [NN]
    float* aggbuf    = Pbuf;                                // overlay: P dead once agg written

    hipMemsetAsync(cnt_i, 0, NN * sizeof(int), stream);
    hipMemsetAsync(cursor, 0, NN * sizeof(int), stream);
    hist_kernel<<<(NE + 255) / 256, 256, 0, stream>>>(receivers, cnt_i);
    inv_kernel<<<(NN + 255) / 256, 256, 0, stream>>>(cnt_i, inv);
    scan1_kernel<<<196, 256, 0, stream>>>(cnt_i, row_start, bsum);
    scan2_kernel<<<1, 256, 0, stream>>>(bsum, 196);
    scan3_kernel<<<196, 256, 0, stream>>>(row_start, bsum);
    scatter_kernel<<<(NE + 255) / 256, 256, 0, stream>>>(receivers, row_start, cursor, eidx);

    for (int l = 0; l < 3; ++l) {
        const float* ncur = (l == 0) ? nodes : nodes_buf;
        const float* ecur = (l == 0) ? edges : edges_buf;
        const float* We_l = We + (size_t)l * 192 * 64;
        // P = nodes @ We[64:128], Q = nodes @ We[128:192]  (round-2 gemm64)
        gemm64_kernel<<<391, 256, 0, stream>>>(ncur, NN, We_l + 64 * 64,
                                               nullptr, nullptr, nullptr, nullptr, nullptr, 0, Pbuf);
        gemm64_kernel<<<391, 256, 0, stream>>>(ncur, NN, We_l + 128 * 64,
                                               nullptr, nullptr, nullptr, nullptr, nullptr, 0, Qbuf);
        // edges = relu(edges @ We[0:64] + P[s] + Q[r] + be)  (register kernel, race-fixed)
        gemm_edge_kernel<<<NE / 256, 256, 0, stream>>>(
            ecur, We_l, be + (size_t)l * 64, Pbuf, Qbuf,
            senders, receivers, edges_buf, NE);
        // agg = segmented-mean(edges)
        agg_kernel<<<2048, 256, 0, stream>>>(edges_buf, eidx, row_start, inv, aggbuf);
        // nodes = relu([nodes|agg] @ Wn + bn)  (round-2 node kernel)
        node_kernel<<<391, 256, 0, stream>>>(ncur, aggbuf,
                                             Wn + (size_t)l * 128 * 64, bn + (size_t)l * 64,
                                             nodes_buf);
    }
    final_kernel<<<625, 256, 0, stream>>>(nodes_buf, gamma, beta,
                                          W1, b1, W2, b2, Wp, bp, out);
}

// Round 6
// 1085.560 us; speedup vs baseline: 1.5035x; 1.5035x over previous
//
#include <hip/hip_runtime.h>

#define NN 50000
#define NE 800000

// ================= CSR build: hist / inv / scan / scatter =================
__global__ void hist_kernel(const int* __restrict__ recv, int* __restrict__ cnt) {
    int i = blockIdx.x * 256 + threadIdx.x;
    if (i < NE) atomicAdd(&cnt[recv[i]], 1);
}

__global__ void inv_kernel(const int* __restrict__ cnt, float* __restrict__ inv) {
    int i = blockIdx.x * 256 + threadIdx.x;
    if (i < NN) inv[i] = 1.0f / (float)max(cnt[i], 1);
}

__global__ void scan1_kernel(const int* __restrict__ cnt, int* __restrict__ excl,
                             int* __restrict__ bsum) {
    const int i = blockIdx.x * 256 + threadIdx.x;
    const int lane = threadIdx.x & 63, wid = threadIdx.x >> 6;
    int orig = (i < NN) ? cnt[i] : 0;
    int x = orig;
    #pragma unroll
    for (int off = 1; off < 64; off <<= 1) {
        int y = __shfl_up(x, off, 64);
        if (lane >= off) x += y;
    }
    __shared__ int ws[4];
    if (lane == 63) ws[wid] = x;
    __syncthreads();
    int add = 0;
    for (int w = 0; w < wid; ++w) add += ws[w];
    x += add;
    if (i < NN) excl[i] = x - orig;
    if (threadIdx.x == 255) bsum[blockIdx.x] = x;
}

__global__ void scan2_kernel(int* __restrict__ bsum, int nb) {
    const int t = threadIdx.x;
    const int lane = t & 63, wid = t >> 6;
    int orig = (t < nb) ? bsum[t] : 0;
    int x = orig;
    #pragma unroll
    for (int off = 1; off < 64; off <<= 1) {
        int y = __shfl_up(x, off, 64);
        if (lane >= off) x += y;
    }
    __shared__ int ws[4];
    if (lane == 63) ws[wid] = x;
    __syncthreads();
    int add = 0;
    for (int w = 0; w < wid; ++w) add += ws[w];
    x += add;
    __syncthreads();
    if (t < nb) bsum[t] = x - orig;
}

__global__ void scan3_kernel(int* __restrict__ excl, const int* __restrict__ bsum) {
    const int i = blockIdx.x * 256 + threadIdx.x;
    if (i < NN) excl[i] += bsum[blockIdx.x];
    if (i == 0) excl[NN] = NE;
}

__global__ void scatter_kernel(const int* __restrict__ recv, const int* __restrict__ row_start,
                               int* __restrict__ cursor, int* __restrict__ eidx) {
    int i = blockIdx.x * 256 + threadIdx.x;
    if (i < NE) {
        int r = recv[i];
        int p = row_start[r] + atomicAdd(&cursor[r], 1);
        eidx[p] = i;
    }
}

// ================= generic M x 64 x 64 GEMM (b128 LDS reads) ==============
// out[e] = maybe_relu(A[e]@W + bias + P[senders[e]] + Q[receivers[e]]).
// Round-2 skeleton (LDS-staged A, proven in-place-safe via the staging
// barrier) with the inner loop upgraded: e-row reads are ds_read_b128 over
// k-quads (stride 68 keeps rows 16B-aligned; 2-way bank aliasing = free).
__launch_bounds__(256, 3)
__global__ void gemm64_kernel(const float* __restrict__ A, int M,
                              const float* __restrict__ W,     // [64][64] k-major
                              const float* __restrict__ bias,  // [64] or null
                              const float* __restrict__ P,     // [NN][64] or null
                              const float* __restrict__ Q,     // [NN][64] or null
                              const int* __restrict__ senders,
                              const int* __restrict__ receivers,
                              int do_relu,
                              float* __restrict__ out) {
    __shared__ float w_lds[64 * 64];      // 16 KB
    __shared__ float e_lds[128 * 68];     // 34.8 KB; stride 68: 16B-aligned, 2-way max
    const int tid = threadIdx.x;
    for (int i = tid; i < 4096; i += 256) w_lds[i] = W[i];
    const int te = tid & 15;
    const int tc = tid >> 4;
    const int c0 = tc * 4;
    float4 bv = make_float4(0.f, 0.f, 0.f, 0.f);
    if (bias) bv = *(const float4*)(bias + c0);
    const int srow = tid >> 1, shalf = tid & 1;
    const int ntiles = (M + 127) >> 7;

    for (int t = blockIdx.x; t < ntiles; t += gridDim.x) {
        const int base = t << 7;
        __syncthreads();   // previous iteration's e_lds reads done
        {
            int g = base + srow;
            if (g > M - 1) g = M - 1;
            const float4* src = (const float4*)(A + (size_t)g * 64) + shalf * 8;
            float4* dst = (float4*)&e_lds[srow * 68 + shalf * 32];
            #pragma unroll
            for (int j = 0; j < 8; ++j) dst[j] = src[j];
        }
        __syncthreads();   // all A-tile reads staged before compute (and before
                           // any aliased out-store later in this iteration)

        float4 acc[8];
        #pragma unroll
        for (int i = 0; i < 8; ++i) acc[i] = make_float4(0.f, 0.f, 0.f, 0.f);

        #pragma unroll 2
        for (int kq = 0; kq < 16; ++kq) {
            float evs[8][4];
            #pragma unroll
            for (int i = 0; i < 8; ++i) {
                const float4 q = *(const float4*)&e_lds[(te + 16 * i) * 68 + kq * 4];
                evs[i][0] = q.x; evs[i][1] = q.y; evs[i][2] = q.z; evs[i][3] = q.w;
            }
            #pragma unroll
            for (int j = 0; j < 4; ++j) {
                const float4 wv = *(const float4*)&w_lds[(kq * 4 + j) * 64 + c0];
                #pragma unroll
                for (int i = 0; i < 8; ++i) {
                    const float ev = evs[i][j];
                    acc[i].x = fmaf(ev, wv.x, acc[i].x);
                    acc[i].y = fmaf(ev, wv.y, acc[i].y);
                    acc[i].z = fmaf(ev, wv.z, acc[i].z);
                    acc[i].w = fmaf(ev, wv.w, acc[i].w);
                }
            }
        }

        #pragma unroll
        for (int i = 0; i < 8; ++i) {
            const int e = base + te + 16 * i;
            if (e < M) {
                float4 o = acc[i];
                o.x += bv.x; o.y += bv.y; o.z += bv.z; o.w += bv.w;
                if (P) {
                    const float4 pv = *(const float4*)(P + (size_t)senders[e] * 64 + c0);
                    o.x += pv.x; o.y += pv.y; o.z += pv.z; o.w += pv.w;
                }
                if (Q) {
                    const float4 qv = *(const float4*)(Q + (size_t)receivers[e] * 64 + c0);
                    o.x += qv.x; o.y += qv.y; o.z += qv.z; o.w += qv.w;
                }
                if (do_relu) {
                    o.x = fmaxf(o.x, 0.f); o.y = fmaxf(o.y, 0.f);
                    o.z = fmaxf(o.z, 0.f); o.w = fmaxf(o.w, 0.f);
                }
                *(float4*)(out + (size_t)e * 64 + c0) = o;
            }
        }
    }
}

// ================= segmented mean aggregation (CSR, atomic-free) ==========
__launch_bounds__(256, 8)
__global__ void agg_kernel(const float* __restrict__ ebuf, const int* __restrict__ eidx,
                           const int* __restrict__ row_start, const float* __restrict__ inv,
                           float* __restrict__ agg) {
    const int lane = threadIdx.x & 63;
    const int w = (blockIdx.x * 256 + threadIdx.x) >> 6;
    const int nw = (gridDim.x * 256) >> 6;
    for (int v = w; v < NN; v += nw) {
        const int s = row_start[v], e = row_start[v + 1];
        float sum = 0.f;
        #pragma unroll 4
        for (int j = s; j < e; ++j) {
            const int ed = eidx[j];
            sum += ebuf[(size_t)ed * 64 + lane];
        }
        agg[(size_t)v * 64 + lane] = sum * inv[v];
    }
}

// ================= node update (round-2): relu([nodes|agg] @ Wn + bn) =====
__launch_bounds__(256, 3)
__global__ void node_kernel(const float* __restrict__ nodes_in,
                            const float* __restrict__ agg,
                            const float* __restrict__ W,     // [128][64]
                            const float* __restrict__ bias,  // [64]
                            float* __restrict__ out) {
    __shared__ float w_lds[128 * 64];
    __shared__ float e_lds[128 * 33];
    const int tid = threadIdx.x;
    for (int i = tid; i < 8192; i += 256) w_lds[i] = W[i];
    const int te = tid & 15, tc = tid >> 4, c0 = tc * 4;
    const float4 bv = *(const float4*)(bias + c0);
    const int srow = tid >> 1, shalf = tid & 1;
    const int ntiles = (NN + 127) >> 7;

    for (int t = blockIdx.x; t < ntiles; t += gridDim.x) {
        const int base = t << 7;
        float4 acc[8];
        #pragma unroll
        for (int i = 0; i < 8; ++i) acc[i] = make_float4(0.f, 0.f, 0.f, 0.f);

        #pragma unroll
        for (int c = 0; c < 4; ++c) {
            const float* src0 = (c < 2) ? nodes_in : agg;
            const int coff = (c & 1) * 32;
            __syncthreads();
            {
                int g = base + srow;
                if (g > NN - 1) g = NN - 1;
                const float4* src = (const float4*)(src0 + (size_t)g * 64 + coff) + shalf * 4;
                float* dst = &e_lds[srow * 33 + shalf * 16];
                #pragma unroll
                for (int j = 0; j < 4; ++j) {
                    float4 v = src[j];
                    dst[j * 4 + 0] = v.x; dst[j * 4 + 1] = v.y;
                    dst[j * 4 + 2] = v.z; dst[j * 4 + 3] = v.w;
                }
            }
            __syncthreads();
            #pragma unroll 4
            for (int k = 0; k < 32; ++k) {
                const float4 wv = *(const float4*)&w_lds[(c * 32 + k) * 64 + c0];
                #pragma unroll
                for (int i = 0; i < 8; ++i) {
                    const float ev = e_lds[(te + 16 * i) * 33 + k];
                    acc[i].x = fmaf(ev, wv.x, acc[i].x);
                    acc[i].y = fmaf(ev, wv.y, acc[i].y);
                    acc[i].z = fmaf(ev, wv.z, acc[i].z);
                    acc[i].w = fmaf(ev, wv.w, acc[i].w);
                }
            }
        }

        #pragma unroll
        for (int i = 0; i < 8; ++i) {
            const int v = base + te + 16 * i;
            if (v < NN) {
                float4 o = acc[i];
                o.x = fmaxf(o.x + bv.x, 0.f); o.y = fmaxf(o.y + bv.y, 0.f);
                o.z = fmaxf(o.z + bv.z, 0.f); o.w = fmaxf(o.w + bv.w, 0.f);
                *(float4*)(out + (size_t)v * 64 + c0) = o;
            }
        }
    }
}

// ================= final: LN + MLP + projection (LDS-broadcast GEMMs) =====
// 16 nodes/tile, 256 threads: r=tid>>4 (row), li=tid&15 (channel group).
// No dynamic shfl; weights in LDS, row values broadcast-read.
__launch_bounds__(256, 2)
__global__ void final_kernel(const float* __restrict__ nodes,
                             const float* __restrict__ gamma,
                             const float* __restrict__ beta,
                             const float* __restrict__ W1, const float* __restrict__ b1,
                             const float* __restrict__ W2, const float* __restrict__ b2,
                             const float* __restrict__ Wp, const float* __restrict__ bp,
                             float* __restrict__ out) {
    __shared__ float w1_lds[64 * 128];   // 32 KB [k][c]
    __shared__ float w2_lds[128 * 64];   // 32 KB [k][c]
    __shared__ float x_lds[16 * 66];
    __shared__ float h_lds[16 * 130];
    const int tid = threadIdx.x;
    for (int i = tid; i < 8192; i += 256) w1_lds[i] = W1[i];
    for (int i = tid; i < 8192; i += 256) w2_lds[i] = W2[i];
    const int r  = tid >> 4;
    const int li = tid & 15;
    const float4 gm4 = *(const float4*)(gamma + li * 4);
    const float4 bt4 = *(const float4*)(beta + li * 4);
    const float4 b1v0 = *(const float4*)(b1 + li * 8);
    const float4 b1v1 = *(const float4*)(b1 + li * 8 + 4);
    const float4 b2v = *(const float4*)(b2 + li * 4);
    const float4 wpv = *(const float4*)(Wp + li * 4);
    const float bp0 = bp[0];

    for (int tile = blockIdx.x; tile < NN / 16; tile += gridDim.x) {
        const int vbase = tile * 16;
        // ---- load + layernorm (thread = row r, cols li*4..+3) ----
        const float4 xv = *(const float4*)(nodes + (size_t)(vbase + r) * 64 + li * 4);
        float s = xv.x + xv.y + xv.z + xv.w;
        #pragma unroll
        for (int off = 1; off < 16; off <<= 1) s += __shfl_xor(s, off, 16);
        const float mu = s * (1.0f / 64.0f);
        const float dx = xv.x - mu, dy = xv.y - mu, dz = xv.z - mu, dw = xv.w - mu;
        float q = dx * dx + dy * dy + dz * dz + dw * dw;
        #pragma unroll
        for (int off = 1; off < 16; off <<= 1) q += __shfl_xor(q, off, 16);
        const float rs = rsqrtf(q * (1.0f / 64.0f) + 1e-5f);
        float* xp = &x_lds[r * 66 + li * 4];
        xp[0] = dx * rs * gm4.x + bt4.x;
        xp[1] = dy * rs * gm4.y + bt4.y;
        xp[2] = dz * rs * gm4.z + bt4.z;
        xp[3] = dw * rs * gm4.w + bt4.w;
        __syncthreads();   // x ready; also: all GEMM1 x-reads of prev tile done

        // ---- GEMM1: h[r][li*8..+7] = relu(x@W1 + b1) ----
        float4 h0 = make_float4(0.f, 0.f, 0.f, 0.f);
        float4 h1 = make_float4(0.f, 0.f, 0.f, 0.f);
        #pragma unroll 8
        for (int k = 0; k < 64; ++k) {
            const float xk = x_lds[r * 66 + k];
            const float4 w0 = *(const float4*)&w1_lds[k * 128 + li * 8];
            const float4 w1v = *(const float4*)&w1_lds[k * 128 + li * 8 + 4];
            h0.x = fmaf(xk, w0.x, h0.x); h0.y = fmaf(xk, w0.y, h0.y);
            h0.z = fmaf(xk, w0.z, h0.z); h0.w = fmaf(xk, w0.w, h0.w);
            h1.x = fmaf(xk, w1v.x, h1.x); h1.y = fmaf(xk, w1v.y, h1.y);
            h1.z = fmaf(xk, w1v.z, h1.z); h1.w = fmaf(xk, w1v.w, h1.w);
        }
        float* hp = &h_lds[r * 130 + li * 8];
        hp[0] = fmaxf(h0.x + b1v0.x, 0.f);
        hp[1] = fmaxf(h0.y + b1v0.y, 0.f);
        hp[2] = fmaxf(h0.z + b1v0.z, 0.f);
        hp[3] = fmaxf(h0.w + b1v0.w, 0.f);
        hp[4] = fmaxf(h1.x + b1v1.x, 0.f);
        hp[5] = fmaxf(h1.y + b1v1.y, 0.f);
        hp[6] = fmaxf(h1.z + b1v1.z, 0.f);
        hp[7] = fmaxf(h1.w + b1v1.w, 0.f);
        __syncthreads();   // h ready

        // ---- GEMM2 + projection: thread (r, li*4..+3) ----
        float4 o = make_float4(0.f, 0.f, 0.f, 0.f);
        #pragma unroll 8
        for (int k = 0; k < 128; ++k) {
            const float hk = h_lds[r * 130 + k];
            const float4 w = *(const float4*)&w2_lds[k * 64 + li * 4];
            o.x = fmaf(hk, w.x, o.x); o.y = fmaf(hk, w.y, o.y);
            o.z = fmaf(hk, w.z, o.z); o.w = fmaf(hk, w.w, o.w);
        }
        float p = (o.x + b2v.x) * wpv.x + (o.y + b2v.y) * wpv.y +
                  (o.z + b2v.z) * wpv.z + (o.w + b2v.w) * wpv.w;
        #pragma unroll
        for (int off = 1; off < 16; off <<= 1) p += __shfl_xor(p, off, 16);
        if (li == 0) out[vbase + r] = p + bp0;
    }
}

extern "C" void kernel_launch(void* const* d_in, const int* in_sizes, int n_in,
                              void* d_out, int out_size, void* d_ws, size_t ws_size,
                              hipStream_t stream) {
    const float* nodes     = (const float*)d_in[0];
    const float* edges     = (const float*)d_in[1];
    const int*   senders   = (const int*)d_in[2];
    const int*   receivers = (const int*)d_in[3];
    const float* We        = (const float*)d_in[4];
    const float* be        = (const float*)d_in[5];
    const float* Wn        = (const float*)d_in[6];
    const float* bn        = (const float*)d_in[7];
    const float* gamma     = (const float*)d_in[8];
    const float* beta      = (const float*)d_in[9];
    const float* W1        = (const float*)d_in[10];
    const float* b1        = (const float*)d_in[11];
    const float* W2        = (const float*)d_in[12];
    const float* b2        = (const float*)d_in[13];
    const float* Wp        = (const float*)d_in[14];
    const float* bp        = (const float*)d_in[15];
    float* out = (float*)d_out;

    float* ws        = (float*)d_ws;
    float* edges_buf = ws;                                  // [NE][64] 204.8 MB
    float* Pbuf      = edges_buf + (size_t)NE * 64;         // [NN][64] (reused as agg)
    float* Qbuf      = Pbuf + (size_t)NN * 64;              // [NN][64]
    float* nodes_buf = Qbuf + (size_t)NN * 64;              // [NN][64]
    int*   cnt_i     = (int*)(nodes_buf + (size_t)NN * 64); // [NN]
    int*   row_start = cnt_i + NN;                          // [NN+1]
    int*   cursor    = row_start + NN + 1;                  // [NN]
    int*   eidx      = cursor + NN;                         // [NE]
    int*   bsum      = eidx + NE;                           // [256]
    float* inv       = (float*)(bsum + 256);                // [NN]
    float* aggbuf    = Pbuf;                                // overlay: P dead once agg written

    hipMemsetAsync(cnt_i, 0, NN * sizeof(int), stream);
    hipMemsetAsync(cursor, 0, NN * sizeof(int), stream);
    hist_kernel<<<(NE + 255) / 256, 256, 0, stream>>>(receivers, cnt_i);
    inv_kernel<<<(NN + 255) / 256, 256, 0, stream>>>(cnt_i, inv);
    scan1_kernel<<<196, 256, 0, stream>>>(cnt_i, row_start, bsum);
    scan2_kernel<<<1, 256, 0, stream>>>(bsum, 196);
    scan3_kernel<<<196, 256, 0, stream>>>(row_start, bsum);
    scatter_kernel<<<(NE + 255) / 256, 256, 0, stream>>>(receivers, row_start, cursor, eidx);

    for (int l = 0; l < 3; ++l) {
        const float* ncur = (l == 0) ? nodes : nodes_buf;
        const float* ecur = (l == 0) ? edges : edges_buf;
        const float* We_l = We + (size_t)l * 192 * 64;
        // P = nodes @ We[64:128], Q = nodes @ We[128:192]
        gemm64_kernel<<<391, 256, 0, stream>>>(ncur, NN, We_l + 64 * 64,
                                               nullptr, nullptr, nullptr, nullptr, nullptr, 0, Pbuf);
        gemm64_kernel<<<391, 256, 0, stream>>>(ncur, NN, We_l + 128 * 64,
                                               nullptr, nullptr, nullptr, nullptr, nullptr, 0, Qbuf);
        // edges = relu(edges @ We[0:64] + P[s] + Q[r] + be)
        gemm64_kernel<<<3125, 256, 0, stream>>>(ecur, NE, We_l,
                                                be + (size_t)l * 64, Pbuf, Qbuf,
                                                senders, receivers, 1, edges_buf);
        // agg = segmented-mean(edges)
        agg_kernel<<<2048, 256, 0, stream>>>(edges_buf, eidx, row_start, inv, aggbuf);
        // nodes = relu([nodes|agg] @ Wn + bn)
        node_kernel<<<391, 256, 0, stream>>>(ncur, aggbuf,
                                             Wn + (size_t)l * 128 * 64, bn + (size_t)l * 64,
                                             nodes_buf);
    }
    final_kernel<<<625, 256, 0, stream>>>(nodes_buf, gamma, beta,
                                          W1, b1, W2, b2, Wp, bp, out);
}

// Round 7
// 808.698 us; speedup vs baseline: 2.0182x; 1.3424x over previous
//
#include <hip/hip_runtime.h>

#define NN 50000
#define NE 800000

// ================= CSR build: hist / inv / scan / scatter =================
__global__ void hist_kernel(const int* __restrict__ recv, int* __restrict__ cnt) {
    int i = blockIdx.x * 256 + threadIdx.x;
    if (i < NE) atomicAdd(&cnt[recv[i]], 1);
}

__global__ void inv_kernel(const int* __restrict__ cnt, float* __restrict__ inv) {
    int i = blockIdx.x * 256 + threadIdx.x;
    if (i < NN) inv[i] = 1.0f / (float)max(cnt[i], 1);
}

__global__ void scan1_kernel(const int* __restrict__ cnt, int* __restrict__ excl,
                             int* __restrict__ bsum) {
    const int i = blockIdx.x * 256 + threadIdx.x;
    const int lane = threadIdx.x & 63, wid = threadIdx.x >> 6;
    int orig = (i < NN) ? cnt[i] : 0;
    int x = orig;
    #pragma unroll
    for (int off = 1; off < 64; off <<= 1) {
        int y = __shfl_up(x, off, 64);
        if (lane >= off) x += y;
    }
    __shared__ int ws[4];
    if (lane == 63) ws[wid] = x;
    __syncthreads();
    int add = 0;
    for (int w = 0; w < wid; ++w) add += ws[w];
    x += add;
    if (i < NN) excl[i] = x - orig;
    if (threadIdx.x == 255) bsum[blockIdx.x] = x;
}

__global__ void scan2_kernel(int* __restrict__ bsum, int nb) {
    const int t = threadIdx.x;
    const int lane = t & 63, wid = t >> 6;
    int orig = (t < nb) ? bsum[t] : 0;
    int x = orig;
    #pragma unroll
    for (int off = 1; off < 64; off <<= 1) {
        int y = __shfl_up(x, off, 64);
        if (lane >= off) x += y;
    }
    __shared__ int ws[4];
    if (lane == 63) ws[wid] = x;
    __syncthreads();
    int add = 0;
    for (int w = 0; w < wid; ++w) add += ws[w];
    x += add;
    __syncthreads();
    if (t < nb) bsum[t] = x - orig;
}

__global__ void scan3_kernel(int* __restrict__ excl, const int* __restrict__ bsum) {
    const int i = blockIdx.x * 256 + threadIdx.x;
    if (i < NN) excl[i] += bsum[blockIdx.x];
    if (i == 0) excl[NN] = NE;
}

__global__ void scatter_kernel(const int* __restrict__ senders, const int* __restrict__ recv,
                               const int* __restrict__ row_start,
                               int* __restrict__ cursor, int* __restrict__ eidx,
                               int* __restrict__ sid, int* __restrict__ rid) {
    int i = blockIdx.x * 256 + threadIdx.x;
    if (i < NE) {
        int r = recv[i];
        int p = row_start[r] + atomicAdd(&cursor[r], 1);
        eidx[p] = i;
        sid[p] = senders[i];
        rid[p] = r;
    }
}

// ================= generic M x 64 x 64 GEMM (for P/Q) =====================
__launch_bounds__(256, 3)
__global__ void gemm64_kernel(const float* __restrict__ A, int M,
                              const float* __restrict__ W,     // [64][64] k-major
                              float* __restrict__ out) {
    __shared__ float w_lds[64 * 64];
    __shared__ float e_lds[128 * 68];
    const int tid = threadIdx.x;
    for (int i = tid; i < 4096; i += 256) w_lds[i] = W[i];
    const int te = tid & 15;
    const int tc = tid >> 4;
    const int c0 = tc * 4;
    const int srow = tid >> 1, shalf = tid & 1;
    const int ntiles = (M + 127) >> 7;

    for (int t = blockIdx.x; t < ntiles; t += gridDim.x) {
        const int base = t << 7;
        __syncthreads();
        {
            int g = base + srow;
            if (g > M - 1) g = M - 1;
            const float4* src = (const float4*)(A + (size_t)g * 64) + shalf * 8;
            float4* dst = (float4*)&e_lds[srow * 68 + shalf * 32];
            #pragma unroll
            for (int j = 0; j < 8; ++j) dst[j] = src[j];
        }
        __syncthreads();

        float4 acc[8];
        #pragma unroll
        for (int i = 0; i < 8; ++i) acc[i] = make_float4(0.f, 0.f, 0.f, 0.f);

        #pragma unroll 2
        for (int kq = 0; kq < 16; ++kq) {
            float evs[8][4];
            #pragma unroll
            for (int i = 0; i < 8; ++i) {
                const float4 q = *(const float4*)&e_lds[(te + 16 * i) * 68 + kq * 4];
                evs[i][0] = q.x; evs[i][1] = q.y; evs[i][2] = q.z; evs[i][3] = q.w;
            }
            #pragma unroll
            for (int j = 0; j < 4; ++j) {
                const float4 wv = *(const float4*)&w_lds[(kq * 4 + j) * 64 + c0];
                #pragma unroll
                for (int i = 0; i < 8; ++i) {
                    const float ev = evs[i][j];
                    acc[i].x = fmaf(ev, wv.x, acc[i].x);
                    acc[i].y = fmaf(ev, wv.y, acc[i].y);
                    acc[i].z = fmaf(ev, wv.z, acc[i].z);
                    acc[i].w = fmaf(ev, wv.w, acc[i].w);
                }
            }
        }

        #pragma unroll
        for (int i = 0; i < 8; ++i) {
            const int e = base + te + 16 * i;
            if (e < M) *(float4*)(out + (size_t)e * 64 + c0) = acc[i];
        }
    }
}

// ============ CSR-fused edge GEMM + ReLU + segment-sum aggregation ========
// Edges live in CSR (receiver-sorted) order. Per 128-row tile:
//   stage A (gather via gidx on layer 0, contiguous after) -> GEMM ->
//   epilogue (bias + P[sid] + Q[rid], relu) -> write out (CSR order) ->
//   stash tile in e_lds -> block segment-sum over the tile's receiver
//   range -> one atomicAdd per (node,channel) touched.
// In-place safe (A==out for l>=1): each block reads/writes only its own
// tile rows; staging barrier orders all reads before any write.
__launch_bounds__(256, 3)
__global__ void edge_csr_kernel(const float* A,
                                const int* __restrict__ gidx,   // eidx (l==0) or null
                                const float* __restrict__ W,    // [64][64]
                                const float* __restrict__ bias, // [64]
                                const float* __restrict__ P,
                                const float* __restrict__ Q,
                                const int* __restrict__ sid,
                                const int* __restrict__ rid,
                                const int* __restrict__ row_start,
                                float* out,
                                float* __restrict__ agg) {
    __shared__ float w_lds[64 * 64];
    __shared__ float e_lds[128 * 68];
    const int tid = threadIdx.x;
    for (int i = tid; i < 4096; i += 256) w_lds[i] = W[i];
    const int te = tid & 15;
    const int tc = tid >> 4;
    const int c0 = tc * 4;
    const float4 bv = *(const float4*)(bias + c0);
    const int srow = tid >> 1, shalf = tid & 1;

    for (int t = blockIdx.x; t < NE / 128; t += gridDim.x) {
        const int base = t << 7;
        __syncthreads();   // prev iteration's e_lds use complete
        {
            const int g = base + srow;
            const int src = gidx ? gidx[g] : g;
            const float4* s4 = (const float4*)(A + (size_t)src * 64) + shalf * 8;
            float4* dst = (float4*)&e_lds[srow * 68 + shalf * 32];
            #pragma unroll
            for (int j = 0; j < 8; ++j) dst[j] = s4[j];
        }
        __syncthreads();   // tile fully staged before compute / any aliased write

        float4 acc[8];
        #pragma unroll
        for (int i = 0; i < 8; ++i) acc[i] = make_float4(0.f, 0.f, 0.f, 0.f);

        #pragma unroll 2
        for (int kq = 0; kq < 16; ++kq) {
            float evs[8][4];
            #pragma unroll
            for (int i = 0; i < 8; ++i) {
                const float4 q = *(const float4*)&e_lds[(te + 16 * i) * 68 + kq * 4];
                evs[i][0] = q.x; evs[i][1] = q.y; evs[i][2] = q.z; evs[i][3] = q.w;
            }
            #pragma unroll
            for (int j = 0; j < 4; ++j) {
                const float4 wv = *(const float4*)&w_lds[(kq * 4 + j) * 64 + c0];
                #pragma unroll
                for (int i = 0; i < 8; ++i) {
                    const float ev = evs[i][j];
                    acc[i].x = fmaf(ev, wv.x, acc[i].x);
                    acc[i].y = fmaf(ev, wv.y, acc[i].y);
                    acc[i].z = fmaf(ev, wv.z, acc[i].z);
                    acc[i].w = fmaf(ev, wv.w, acc[i].w);
                }
            }
        }

        __syncthreads();   // all A-reads of e_lds done -> reuse e_lds for outputs

        #pragma unroll
        for (int i = 0; i < 8; ++i) {
            const int e = base + te + 16 * i;
            const int s = sid[e];
            const int r = rid[e];
            const float4 pv = *(const float4*)(P + (size_t)s * 64 + c0);
            const float4 qv = *(const float4*)(Q + (size_t)r * 64 + c0);
            float4 o;
            o.x = fmaxf(acc[i].x + bv.x + pv.x + qv.x, 0.f);
            o.y = fmaxf(acc[i].y + bv.y + pv.y + qv.y, 0.f);
            o.z = fmaxf(acc[i].z + bv.z + pv.z + qv.z, 0.f);
            o.w = fmaxf(acc[i].w + bv.w + pv.w + qv.w, 0.f);
            *(float4*)(out + (size_t)e * 64 + c0) = o;
            *(float4*)&e_lds[(te + 16 * i) * 68 + c0] = o;
        }
        __syncthreads();   // output tile fully in e_lds

        // segment-sum over this tile's receiver range (rid sorted ascending)
        const int v0 = rid[base];
        const int v1 = rid[base + 127];
        const int nv = v1 - v0 + 1;
        for (int idx = tid; idx < nv * 16; idx += 256) {
            const int v  = v0 + (idx >> 4);
            const int cg = (idx & 15) * 4;
            int lo = row_start[v], hi = row_start[v + 1];
            lo = lo > base ? lo : base;
            hi = hi < base + 128 ? hi : base + 128;
            if (lo < hi) {
                float4 sum = make_float4(0.f, 0.f, 0.f, 0.f);
                for (int j = lo - base; j < hi - base; ++j) {
                    const float4 ev = *(const float4*)&e_lds[j * 68 + cg];
                    sum.x += ev.x; sum.y += ev.y; sum.z += ev.z; sum.w += ev.w;
                }
                float* ap = agg + (size_t)v * 64 + cg;
                atomicAdd(ap + 0, sum.x);
                atomicAdd(ap + 1, sum.y);
                atomicAdd(ap + 2, sum.z);
                atomicAdd(ap + 3, sum.w);
            }
        }
    }
}

// ====== node update: relu([nodes | agg*inv] @ Wn + bn), K=128 =============
__launch_bounds__(256, 3)
__global__ void node_kernel(const float* __restrict__ nodes_in,
                            const float* __restrict__ agg,   // raw sums
                            const float* __restrict__ inv,   // 1/max(count,1)
                            const float* __restrict__ W,     // [128][64]
                            const float* __restrict__ bias,  // [64]
                            float* __restrict__ out) {
    __shared__ float w_lds[128 * 64];
    __shared__ float e_lds[128 * 33];
    const int tid = threadIdx.x;
    for (int i = tid; i < 8192; i += 256) w_lds[i] = W[i];
    const int te = tid & 15, tc = tid >> 4, c0 = tc * 4;
    const float4 bv = *(const float4*)(bias + c0);
    const int srow = tid >> 1, shalf = tid & 1;
    const int ntiles = (NN + 127) >> 7;

    for (int t = blockIdx.x; t < ntiles; t += gridDim.x) {
        const int base = t << 7;
        float4 acc[8];
        #pragma unroll
        for (int i = 0; i < 8; ++i) acc[i] = make_float4(0.f, 0.f, 0.f, 0.f);

        #pragma unroll
        for (int c = 0; c < 4; ++c) {
            const float* src0 = (c < 2) ? nodes_in : agg;
            const int coff = (c & 1) * 32;
            __syncthreads();
            {
                int g = base + srow;
                if (g > NN - 1) g = NN - 1;
                const float4* src = (const float4*)(src0 + (size_t)g * 64 + coff) + shalf * 4;
                const float scale = (c >= 2) ? inv[g] : 1.0f;
                float* dst = &e_lds[srow * 33 + shalf * 16];
                #pragma unroll
                for (int j = 0; j < 4; ++j) {
                    float4 v = src[j];
                    dst[j * 4 + 0] = v.x * scale; dst[j * 4 + 1] = v.y * scale;
                    dst[j * 4 + 2] = v.z * scale; dst[j * 4 + 3] = v.w * scale;
                }
            }
            __syncthreads();
            #pragma unroll 4
            for (int k = 0; k < 32; ++k) {
                const float4 wv = *(const float4*)&w_lds[(c * 32 + k) * 64 + c0];
                #pragma unroll
                for (int i = 0; i < 8; ++i) {
                    const float ev = e_lds[(te + 16 * i) * 33 + k];
                    acc[i].x = fmaf(ev, wv.x, acc[i].x);
                    acc[i].y = fmaf(ev, wv.y, acc[i].y);
                    acc[i].z = fmaf(ev, wv.z, acc[i].z);
                    acc[i].w = fmaf(ev, wv.w, acc[i].w);
                }
            }
        }

        #pragma unroll
        for (int i = 0; i < 8; ++i) {
            const int v = base + te + 16 * i;
            if (v < NN) {
                float4 o = acc[i];
                o.x = fmaxf(o.x + bv.x, 0.f); o.y = fmaxf(o.y + bv.y, 0.f);
                o.z = fmaxf(o.z + bv.z, 0.f); o.w = fmaxf(o.w + bv.w, 0.f);
                *(float4*)(out + (size_t)v * 64 + c0) = o;
            }
        }
    }
}

// ================= final: LN + MLP + projection (LDS-broadcast GEMMs) =====
__launch_bounds__(256, 2)
__global__ void final_kernel(const float* __restrict__ nodes,
                             const float* __restrict__ gamma,
                             const float* __restrict__ beta,
                             const float* __restrict__ W1, const float* __restrict__ b1,
                             const float* __restrict__ W2, const float* __restrict__ b2,
                             const float* __restrict__ Wp, const float* __restrict__ bp,
                             float* __restrict__ out) {
    __shared__ float w1_lds[64 * 128];
    __shared__ float w2_lds[128 * 64];
    __shared__ float x_lds[16 * 66];
    __shared__ float h_lds[16 * 130];
    const int tid = threadIdx.x;
    for (int i = tid; i < 8192; i += 256) w1_lds[i] = W1[i];
    for (int i = tid; i < 8192; i += 256) w2_lds[i] = W2[i];
    const int r  = tid >> 4;
    const int li = tid & 15;
    const float4 gm4 = *(const float4*)(gamma + li * 4);
    const float4 bt4 = *(const float4*)(beta + li * 4);
    const float4 b1v0 = *(const float4*)(b1 + li * 8);
    const float4 b1v1 = *(const float4*)(b1 + li * 8 + 4);
    const float4 b2v = *(const float4*)(b2 + li * 4);
    const float4 wpv = *(const float4*)(Wp + li * 4);
    const float bp0 = bp[0];

    for (int tile = blockIdx.x; tile < NN / 16; tile += gridDim.x) {
        const int vbase = tile * 16;
        const float4 xv = *(const float4*)(nodes + (size_t)(vbase + r) * 64 + li * 4);
        float s = xv.x + xv.y + xv.z + xv.w;
        #pragma unroll
        for (int off = 1; off < 16; off <<= 1) s += __shfl_xor(s, off, 16);
        const float mu = s * (1.0f / 64.0f);
        const float dx = xv.x - mu, dy = xv.y - mu, dz = xv.z - mu, dw = xv.w - mu;
        float q = dx * dx + dy * dy + dz * dz + dw * dw;
        #pragma unroll
        for (int off = 1; off < 16; off <<= 1) q += __shfl_xor(q, off, 16);
        const float rs = rsqrtf(q * (1.0f / 64.0f) + 1e-5f);
        float* xp = &x_lds[r * 66 + li * 4];
        xp[0] = dx * rs * gm4.x + bt4.x;
        xp[1] = dy * rs * gm4.y + bt4.y;
        xp[2] = dz * rs * gm4.z + bt4.z;
        xp[3] = dw * rs * gm4.w + bt4.w;
        __syncthreads();

        float4 h0 = make_float4(0.f, 0.f, 0.f, 0.f);
        float4 h1 = make_float4(0.f, 0.f, 0.f, 0.f);
        #pragma unroll 8
        for (int k = 0; k < 64; ++k) {
            const float xk = x_lds[r * 66 + k];
            const float4 w0 = *(const float4*)&w1_lds[k * 128 + li * 8];
            const float4 w1v = *(const float4*)&w1_lds[k * 128 + li * 8 + 4];
            h0.x = fmaf(xk, w0.x, h0.x); h0.y = fmaf(xk, w0.y, h0.y);
            h0.z = fmaf(xk, w0.z, h0.z); h0.w = fmaf(xk, w0.w, h0.w);
            h1.x = fmaf(xk, w1v.x, h1.x); h1.y = fmaf(xk, w1v.y, h1.y);
            h1.z = fmaf(xk, w1v.z, h1.z); h1.w = fmaf(xk, w1v.w, h1.w);
        }
        float* hp = &h_lds[r * 130 + li * 8];
        hp[0] = fmaxf(h0.x + b1v0.x, 0.f);
        hp[1] = fmaxf(h0.y + b1v0.y, 0.f);
        hp[2] = fmaxf(h0.z + b1v0.z, 0.f);
        hp[3] = fmaxf(h0.w + b1v0.w, 0.f);
        hp[4] = fmaxf(h1.x + b1v1.x, 0.f);
        hp[5] = fmaxf(h1.y + b1v1.y, 0.f);
        hp[6] = fmaxf(h1.z + b1v1.z, 0.f);
        hp[7] = fmaxf(h1.w + b1v1.w, 0.f);
        __syncthreads();

        float4 o = make_float4(0.f, 0.f, 0.f, 0.f);
        #pragma unroll 8
        for (int k = 0; k < 128; ++k) {
            const float hk = h_lds[r * 130 + k];
            const float4 w = *(const float4*)&w2_lds[k * 64 + li * 4];
            o.x = fmaf(hk, w.x, o.x); o.y = fmaf(hk, w.y, o.y);
            o.z = fmaf(hk, w.z, o.z); o.w = fmaf(hk, w.w, o.w);
        }
        float p = (o.x + b2v.x) * wpv.x + (o.y + b2v.y) * wpv.y +
                  (o.z + b2v.z) * wpv.z + (o.w + b2v.w) * wpv.w;
        #pragma unroll
        for (int off = 1; off < 16; off <<= 1) p += __shfl_xor(p, off, 16);
        if (li == 0) out[vbase + r] = p + bp0;
    }
}

extern "C" void kernel_launch(void* const* d_in, const int* in_sizes, int n_in,
                              void* d_out, int out_size, void* d_ws, size_t ws_size,
                              hipStream_t stream) {
    const float* nodes     = (const float*)d_in[0];
    const float* edges     = (const float*)d_in[1];
    const int*   senders   = (const int*)d_in[2];
    const int*   receivers = (const int*)d_in[3];
    const float* We        = (const float*)d_in[4];
    const float* be        = (const float*)d_in[5];
    const float* Wn        = (const float*)d_in[6];
    const float* bn        = (const float*)d_in[7];
    const float* gamma     = (const float*)d_in[8];
    const float* beta      = (const float*)d_in[9];
    const float* W1        = (const float*)d_in[10];
    const float* b1        = (const float*)d_in[11];
    const float* W2        = (const float*)d_in[12];
    const float* b2        = (const float*)d_in[13];
    const float* Wp        = (const float*)d_in[14];
    const float* bp        = (const float*)d_in[15];
    float* out = (float*)d_out;

    float* ws        = (float*)d_ws;
    float* edges_buf = ws;                                   // [NE][64]  204.8 MB (CSR order)
    float* Pbuf      = edges_buf + (size_t)NE * 64;          // [NN][64]
    float* Qbuf      = Pbuf + (size_t)NN * 64;               // [NN][64]
    float* nodes_buf = Qbuf + (size_t)NN * 64;               // [NN][64]
    float* aggbuf    = nodes_buf + (size_t)NN * 64;          // [NN][64] raw sums
    int*   cnt_i     = (int*)(aggbuf + (size_t)NN * 64);     // [NN]
    int*   row_start = cnt_i + NN;                           // [NN+1]
    int*   cursor    = row_start + NN + 1;                   // [NN]
    int*   eidx      = cursor + NN;                          // [NE]
    int*   sid       = eidx + NE;                            // [NE]
    int*   rid       = sid + NE;                             // [NE]
    int*   bsum      = rid + NE;                             // [256]
    float* inv       = (float*)(bsum + 256);                 // [NN]

    hipMemsetAsync(cnt_i, 0, NN * sizeof(int), stream);
    hipMemsetAsync(cursor, 0, NN * sizeof(int), stream);
    hist_kernel<<<(NE + 255) / 256, 256, 0, stream>>>(receivers, cnt_i);
    inv_kernel<<<(NN + 255) / 256, 256, 0, stream>>>(cnt_i, inv);
    scan1_kernel<<<196, 256, 0, stream>>>(cnt_i, row_start, bsum);
    scan2_kernel<<<1, 256, 0, stream>>>(bsum, 196);
    scan3_kernel<<<196, 256, 0, stream>>>(row_start, bsum);
    scatter_kernel<<<(NE + 255) / 256, 256, 0, stream>>>(senders, receivers, row_start,
                                                         cursor, eidx, sid, rid);

    for (int l = 0; l < 3; ++l) {
        const float* ncur = (l == 0) ? nodes : nodes_buf;
        const float* We_l = We + (size_t)l * 192 * 64;
        // P = nodes @ We[64:128], Q = nodes @ We[128:192]
        gemm64_kernel<<<391, 256, 0, stream>>>(ncur, NN, We_l + 64 * 64, Pbuf);
        gemm64_kernel<<<391, 256, 0, stream>>>(ncur, NN, We_l + 128 * 64, Qbuf);
        // zero agg sums, then fused edge GEMM + aggregation (CSR order)
        hipMemsetAsync(aggbuf, 0, (size_t)NN * 64 * sizeof(float), stream);
        edge_csr_kernel<<<3125, 256, 0, stream>>>(
            (l == 0) ? edges : edges_buf,
            (l == 0) ? eidx : (const int*)nullptr,
            We_l, be + (size_t)l * 64, Pbuf, Qbuf,
            sid, rid, row_start, edges_buf, aggbuf);
        // nodes = relu([nodes | agg*inv] @ Wn + bn)
        node_kernel<<<391, 256, 0, stream>>>(ncur, aggbuf, inv,
                                             Wn + (size_t)l * 128 * 64, bn + (size_t)l * 64,
                                             nodes_buf);
    }
    final_kernel<<<625, 256, 0, stream>>>(nodes_buf, gamma, beta,
                                          W1, b1, W2, b2, Wp, bp, out);
}